// Round 10
// baseline (719.017 us; speedup 1.0000x reference)
//
#include <hip/hip_runtime.h>
#include <math.h>

#define B_ 2
#define S_ 128
#define H_ 4
#define DK_ 128
#define NB_ 4
#define D_ 512
#define M_ 256   // B_*S_

typedef __attribute__((ext_vector_type(8))) short short8;
typedef __attribute__((ext_vector_type(4))) float float4v;
typedef __attribute__((ext_vector_type(4))) unsigned short ushort4v;

__device__ __forceinline__ float elu1(float x) {
    return (x > 0.f) ? (x + 1.f) : __expf(x);
}

__device__ __forceinline__ unsigned short f2bf(float f) {
    unsigned u = __float_as_uint(f);
    unsigned r = (u + 0x7FFFu + ((u >> 16) & 1u)) >> 16;
    return (unsigned short)r;
}

// Monotonic grid barrier. Correctness-critical differences vs the failed R4
// version: (1) EVERY thread executes __threadfence() on both the release and
// acquire side (emits the L1/L2 maintenance per-wave), (2) the ticket/spin use
// agent-scope acq/rel atomics. Counter is monotone -> graph-replay safe.
__device__ unsigned g_bar = 0;

__device__ __forceinline__ void gbar(unsigned nblk) {
    __syncthreads();
    __threadfence();   // release: all threads drain + write-back
    if (threadIdx.x == 0) {
        unsigned ticket = __hip_atomic_fetch_add(&g_bar, 1u, __ATOMIC_ACQ_REL,
                                                 __HIP_MEMORY_SCOPE_AGENT) + 1u;
        unsigned tgt = ((ticket + nblk - 1u) / nblk) * nblk;
        while (__hip_atomic_load(&g_bar, __ATOMIC_ACQUIRE,
                                 __HIP_MEMORY_SCOPE_AGENT) < tgt) {
            __builtin_amdgcn_s_sleep(2);
        }
    }
    __syncthreads();
    __threadfence();   // acquire: all threads invalidate before next phase reads
}

// ---------------------------------------------------------------------------
// ws layout (float offsets) — identical to R9
//  qkv 786432@0 | pq 131072@786432 | pk 131072@917504 | bbq 16384@1048576
//  bbk 16384@1064960 | fKm 524288@1081344 | fKs 524288@1605632
//  y_m 131072@2129920 | y_c 131072@2260992 | A_m 131072@2392064
//  A_c 131072@2523136 | Wt 1572864@2654208 | wm_bf 131072@4227072
//  wc_bf 131072@4358144 | mctxb 65536@4489216 | cctxb 65536@4554752
//  pm_bf 65536@4620288 | bbm_bf 8192@4685824 | w4_bf 32768@4694016
// ---------------------------------------------------------------------------

struct Args {
    const float *x_m, *x_c, *b_m, *b_c, *bb_c, *p_m, *p_c, *bb_m;
    const float *W_xm, *W_xc, *W_bm, *W_bc;
    const float *Wq1_w, *Wq1_b, *Wq2_w, *Wq2_b, *Wk1_w, *Wk1_b, *Wk2_w, *Wk2_b;
    const float *mean_w, *mean_b, *cov_w, *cov_b, *ln_w, *ln_b;
    const int *b_seq;
    float *qkv, *pq, *pk, *bbq, *bbk, *fKm, *fKs, *y_m, *y_c, *out;
    unsigned short *A_m, *A_c, *Wt, *wm_bf, *wc_bf, *mctxb, *cctxb;
    unsigned short *pm_bf, *bbm_bf, *w4_bf;
};

union __attribute__((aligned(16))) SMem {
    unsigned short tile[32][33];                                   // P0-B
    struct { float qm[2][528]; float qs[2][528]; float red[2][4];
             float pr[2][128]; float pr2[2][128]; } a;             // P3 (~10.6KB)
    float red8[8];                                                 // P5
};

__global__ __launch_bounds__(256, 2) void mega(Args g)
{
    __shared__ SMem sm;
    const int t = threadIdx.x;
    const int blk = blockIdx.x;
    const unsigned NBK = gridDim.x;     // 256 or 512
    const int wv = t >> 6, lane = t & 63;
    const int u2 = t >> 7, tl = t & 127;
    const int l15 = lane & 15, quad = lane >> 4;
    const float eps = 1e-24f;

    // ===================== P0-A: bf16 conversions (315392 chunks) ==========
    for (int cid = blk * 256 + t; cid < 315392; cid += NBK * 256) {
        const float* srcp;
        unsigned short* dstp;
        if (cid < 262144) {
            int job = cid >> 16;
            int off = (cid & 65535) * 4;
            if (job <= 1) {
                int m = off >> 10, k = off & 1023;
                if (job == 0) { srcp = (k < 512) ? (g.x_m + m * 512 + k) : (g.b_m + m * 512 + k - 512); dstp = g.A_m + off; }
                else          { srcp = (k < 512) ? (g.x_c + m * 512 + k) : (g.b_c + m * 512 + k - 512); dstp = g.A_c + off; }
            } else if (job == 2) { srcp = g.mean_w + off; dstp = g.wm_bf + off; }
            else                 { srcp = g.cov_w + off;  dstp = g.wc_bf + off; }
        } else if (cid < 294912) {
            int off = (cid - 262144) * 4;
            srcp = g.p_m + off; dstp = g.pm_bf + off;
        } else if (cid < 299008) {
            int off = (cid - 294912) * 4;
            srcp = g.bb_m + off; dstp = g.bbm_bf + off;
        } else {
            int off = (cid - 299008) * 4;
            int seg = off >> 14;
            const float* Ws = (seg == 0) ? g.Wq2_w : (seg == 1) ? g.Wk2_w : (seg == 2) ? g.Wq1_w : g.Wk1_w;
            srcp = Ws + (off & 16383); dstp = g.w4_bf + off;
        }
        float4 v = *(const float4*)srcp;
        ushort4v o4;
        o4.x = f2bf(v.x); o4.y = f2bf(v.y); o4.z = f2bf(v.z); o4.w = f2bf(v.w);
        *(ushort4v*)dstp = o4;
    }
    // ===================== P0-B: Wt transpose (3072 tiles, exact div) ======
    {
        const int tx = t & 31, ty = t >> 5;
        for (int tid = blk; tid < 3072; tid += NBK) {
            int nt = tid & 15, kt = (tid >> 4) & 15, z = tid >> 8;
            int o = z >> 1, part = z & 1;
            const float* src;
            if (part == 0) src = (o < 3) ? (g.W_xm + o * 262144) : (g.W_xc + (o - 3) * 262144);
            else           src = (o < 3) ? (g.W_bm + o * 262144) : (g.W_bc + (o - 3) * 262144);
            __syncthreads();
#pragma unroll
            for (int u = 0; u < 4; ++u)
                sm.tile[ty + u * 8][tx] = f2bf(src[(kt * 32 + ty + u * 8) * 512 + nt * 32 + tx]);
            __syncthreads();
            unsigned short* dst = g.Wt + o * 524288 + part * 512;
#pragma unroll
            for (int u = 0; u < 4; ++u)
                dst[(nt * 32 + ty + u * 8) * 1024 + kt * 32 + tx] = sm.tile[tx][ty + u * 8];
        }
    }

    gbar(NBK);   // ---- A/Wt ready ----

    // ===================== P1: MFMA GEMMs (4224 wave-jobs) =================
    for (int wid = blk * 4 + wv; wid < 4224; wid += NBK * 4) {
        if (wid < 3072) {
            const int o = wid >> 9;
            const int rem = wid & 511;
            const int nt = rem & 31, mt = rem >> 5;
            const int m0 = mt * 16, n0 = nt * 16;

            const unsigned short* A = (o < 3) ? g.A_m : g.A_c;
            const unsigned short* ap = A + (m0 + l15) * 1024 + quad * 8;
            const unsigned short* bp = g.Wt + o * 524288 + (n0 + l15) * 1024 + quad * 8;

            float4v acc0 = {0.f, 0.f, 0.f, 0.f};
            float4v acc1 = {0.f, 0.f, 0.f, 0.f};
#pragma unroll
            for (int k0 = 0; k0 < 1024; k0 += 64) {
                short8 a0 = *(const short8*)(ap + k0);
                short8 b0 = *(const short8*)(bp + k0);
                short8 a1 = *(const short8*)(ap + k0 + 32);
                short8 b1 = *(const short8*)(bp + k0 + 32);
                acc0 = __builtin_amdgcn_mfma_f32_16x16x32_bf16(a0, b0, acc0, 0, 0, 0);
                acc1 = __builtin_amdgcn_mfma_f32_16x16x32_bf16(a1, b1, acc1, 0, 0, 0);
            }
            float* dst = g.qkv + o * 131072;
#pragma unroll
            for (int r = 0; r < 4; ++r) {
                float v = acc0[r] + acc1[r];
                if (o >= 3) v = elu1(v);
                dst[(m0 + quad * 4 + r) * 512 + n0 + l15] = v;
            }
        } else {
            const unsigned short* Abf;
            const unsigned short* Wb;
            const float* bias;
            float* dst;
            int m0, n0, h;
            if (wid < 4096) {
                int lid = wid - 3072;
                int sel = lid >> 9;
                int r = lid & 511;
                h = r >> 7;
                int rem = r & 127;
                m0 = (rem >> 3) * 16; n0 = (rem & 7) * 16;
                Abf = g.pm_bf;
                Wb = g.w4_bf + sel * 16384;
                bias = sel ? g.Wk2_b : g.Wq2_b;
                dst = sel ? g.pk : g.pq;
            } else {
                int lid = wid - 4096;
                int sel = lid >> 6;
                int r = lid & 63;
                h = r >> 4;
                int rem = r & 15;
                m0 = (rem >> 3) * 16; n0 = (rem & 7) * 16;
                Abf = g.bbm_bf;
                Wb = g.w4_bf + 32768 + sel * 16384;
                bias = sel ? g.Wk1_b : g.Wq1_b;
                dst = sel ? g.bbk : g.bbq;
            }
            const unsigned short* ap = Abf + (m0 + l15) * 512 + h * 128 + quad * 8;
            const unsigned short* bp = Wb + (n0 + l15) * 128 + quad * 8;

            float4v acc0 = {0.f, 0.f, 0.f, 0.f};
            float4v acc1 = {0.f, 0.f, 0.f, 0.f};
#pragma unroll
            for (int k0 = 0; k0 < 128; k0 += 64) {
                short8 a0 = *(const short8*)(ap + k0);
                short8 b0 = *(const short8*)(bp + k0);
                short8 a1 = *(const short8*)(ap + k0 + 32);
                short8 b1 = *(const short8*)(bp + k0 + 32);
                acc0 = __builtin_amdgcn_mfma_f32_16x16x32_bf16(a0, b0, acc0, 0, 0, 0);
                acc1 = __builtin_amdgcn_mfma_f32_16x16x32_bf16(a1, b1, acc1, 0, 0, 0);
            }
            float bv = bias[n0 + l15];
#pragma unroll
            for (int r = 0; r < 4; ++r)
                dst[(m0 + quad * 4 + r) * 512 + h * 128 + n0 + l15] = acc0[r] + acc1[r] + bv;
        }
    }

    gbar(NBK);   // ---- qkv/pq/pk/bbq/bbk ready ----

    // ===================== P2: fK precompute (1024 half-block units) =======
    for (int unit = blk * 2 + u2; unit < 1024; unit += NBK * 2) {
        int j = unit & 127, h = (unit >> 7) & 3, b = unit >> 9;
        int d = h * 128 + tl;
        int base = (b * S_ + j) * D_ + d;
        int sj = g.b_seq[b * S_ + j];

        float m1 = g.qkv[M_ * D_ + base];
        float c1 = g.qkv[4 * M_ * D_ + base];
        float m3 = g.pk[base];
        float c3 = g.p_c[base];

        float p1 = 1.f / fmaxf(c1, eps);
        float p3 = 1.f / fmaxf(c3, eps);
        float mp13 = m1 * p1 + m3 * p3;

#pragma unroll
        for (int sv = 0; sv < 4; ++sv) {
            int idx = (b * 16 + sj * 4 + sv) * 512 + d;
            float m2 = g.bbk[idx];
            float c2 = g.bb_c[idx];
            float p2 = 1.f / fmaxf(c2, eps);
            float cc = 1.f / (p1 + p2 + p3);
            int o = (((b * H_ + h) * 4 + sv) * S_ + j) * 128 + tl;
            g.fKm[o] = cc * (mp13 + m2 * p2);
            g.fKs[o] = sqrtf(fmaxf(cc, eps));
        }
    }

    gbar(NBK);   // ---- fK ready ----

    // ===================== P3: attn (1024 half-block units, exact div) =====
    {
        float* qm = sm.a.qm[u2];
        float* qs = sm.a.qs[u2];
        float* red = sm.a.red[u2];
        float* pr = sm.a.pr[u2];
        float* pr2 = sm.a.pr2[u2];

        for (int unit = blk * 2 + u2; unit < 1024; unit += NBK * 2) {
            int i = unit & 127, h = (unit >> 7) & 3, b = unit >> 9;

            __syncthreads();
            const int si = g.b_seq[b * S_ + i];
            const int sj = g.b_seq[b * S_ + tl];

            {
                const int d = h * 128 + tl;
                const int base = (b * S_ + i) * D_ + d;
                float m1 = g.qkv[base];
                float c1 = g.qkv[3 * M_ * D_ + base];
                float m3 = g.pq[base];
                float c3 = g.p_c[base];
                float p1 = 1.f / fmaxf(c1, eps);
                float p3 = 1.f / fmaxf(c3, eps);
                float mp13 = m1 * p1 + m3 * p3;
#pragma unroll
                for (int sv = 0; sv < 4; ++sv) {
                    int idx = (b * 16 + sv * 4 + si) * 512 + d;
                    float m2 = g.bbq[idx];
                    float c2 = g.bb_c[idx];
                    float p2 = 1.f / fmaxf(c2, eps);
                    float cc = 1.f / (p1 + p2 + p3);
                    qm[sv * 132 + tl] = cc * (mp13 + m2 * p2);
                    qs[sv * 132 + tl] = sqrtf(fmaxf(cc, eps));
                }
            }
            __syncthreads();

            const int krow = (((b * H_ + h) * 4 + si) * S_ + tl) * 128;
            const float4* kmp = (const float4*)(g.fKm + krow);
            const float4* ksp = (const float4*)(g.fKs + krow);

            float w2 = 0.f;
#pragma unroll 4
            for (int k4 = 0; k4 < 32; ++k4) {
                float4 km = kmp[k4];
                float4 ks = ksp[k4];
                float4 m = *(const float4*)&qm[sj * 132 + k4 * 4];
                float4 s = *(const float4*)&qs[sj * 132 + k4 * 4];
                float d0 = m.x - km.x, d1 = m.y - km.y, d2 = m.z - km.z, d3 = m.w - km.w;
                float e0 = s.x - ks.x, e1 = s.y - ks.y, e2 = s.z - ks.z, e3 = s.w - ks.w;
                w2 += d0 * d0 + d1 * d1 + d2 * d2 + d3 * d3
                    + e0 * e0 + e1 * e1 + e2 * e2 + e3 * e3;
            }
            float score = -w2 * 0.08838834764831845f;

            float mx = score;
#pragma unroll
            for (int off = 32; off >= 1; off >>= 1) mx = fmaxf(mx, __shfl_xor(mx, off));
            if ((tl & 63) == 0) red[tl >> 6] = mx;
            __syncthreads();
            mx = fmaxf(red[0], red[1]);
            float e = __expf(score - mx);
            float smv = e;
#pragma unroll
            for (int off = 32; off >= 1; off >>= 1) smv += __shfl_xor(smv, off);
            if ((tl & 63) == 0) red[2 + (tl >> 6)] = smv;
            __syncthreads();
            float p = e / (red[2] + red[3]);

            g.out[262144 + ((b * H_ + h) * S_ + i) * S_ + tl] = p;
            pr[tl] = p;
            pr2[tl] = p * p;
            __syncthreads();

            const float* v1 = g.qkv + 2 * M_ * D_ + (b * S_) * D_ + h * 128 + tl;
            const float* v2 = g.qkv + 5 * M_ * D_ + (b * S_) * D_ + h * 128 + tl;
            float am = 0.f, ac = 0.f;
#pragma unroll 8
            for (int j = 0; j < 128; ++j) {
                am = fmaf(pr[j], v1[j * D_], am);
                ac = fmaf(pr2[j], v2[j * D_], ac);
            }
            g.mctxb[(b * S_ + i) * D_ + h * 128 + tl] = f2bf(am);
            g.cctxb[(b * S_ + i) * D_ + h * 128 + tl] = f2bf(ac);
        }
    }

    gbar(NBK);   // ---- ctx ready ----

    // ===================== P4: epilogue MFMA GEMM (1024 wave-jobs) =========
    for (int wid = blk * 4 + wv; wid < 1024; wid += NBK * 4) {
        int mat = wid >> 9;
        int rem = wid & 511;
        int nt = rem & 31, mt = rem >> 5;
        int m0 = mt * 16, n0 = nt * 16;

        const unsigned short* A = mat ? g.cctxb : g.mctxb;
        const unsigned short* Bw = mat ? g.wc_bf : g.wm_bf;
        float* y = mat ? g.y_c : g.y_m;

        const unsigned short* ap = A + (m0 + l15) * 512 + quad * 8;
        const unsigned short* bp = Bw + (n0 + l15) * 512 + quad * 8;

        float4v acc0 = {0.f, 0.f, 0.f, 0.f};
        float4v acc1 = {0.f, 0.f, 0.f, 0.f};
#pragma unroll
        for (int k0 = 0; k0 < 512; k0 += 64) {
            short8 a0 = *(const short8*)(ap + k0);
            short8 b0 = *(const short8*)(bp + k0);
            short8 a1 = *(const short8*)(ap + k0 + 32);
            short8 b1 = *(const short8*)(bp + k0 + 32);
            acc0 = __builtin_amdgcn_mfma_f32_16x16x32_bf16(a0, b0, acc0, 0, 0, 0);
            acc1 = __builtin_amdgcn_mfma_f32_16x16x32_bf16(a1, b1, acc1, 0, 0, 0);
        }
#pragma unroll
        for (int r = 0; r < 4; ++r)
            y[(m0 + quad * 4 + r) * 512 + n0 + l15] = acc0[r] + acc1[r];
    }

    gbar(NBK);   // ---- y ready ----

    // ===================== P5: bias + residual + LN (512 rows, exact div) ==
    for (int id = blk; id < 512; id += NBK) {
        int mat = id >> 8, row = id & 255;
        const float* yg = mat ? g.y_c : g.y_m;
        const float* bias = mat ? g.cov_b : g.mean_b;
        const float* res = mat ? g.x_c : g.x_m;
        const int base = row * 512;

        float y0 = yg[base + t] + bias[t] + res[base + t];
        float y1 = yg[base + 256 + t] + bias[256 + t] + res[base + 256 + t];
        float s = y0 + y1, ss = y0 * y0 + y1 * y1;
#pragma unroll
        for (int off = 32; off >= 1; off >>= 1) { s += __shfl_xor(s, off); ss += __shfl_xor(ss, off); }
        if ((t & 63) == 0) { sm.red8[t >> 6] = s; sm.red8[4 + (t >> 6)] = ss; }
        __syncthreads();
        float mu = (sm.red8[0] + sm.red8[1] + sm.red8[2] + sm.red8[3]) * (1.f / 512.f);
        float var = (sm.red8[4] + sm.red8[5] + sm.red8[6] + sm.red8[7]) * (1.f / 512.f) - mu * mu;
        float rstd = 1.f / sqrtf(var + 1e-12f);
        g.out[mat * 131072 + base + t] = (y0 - mu) * rstd * g.ln_w[t] + g.ln_b[t];
        g.out[mat * 131072 + base + 256 + t] = (y1 - mu) * rstd * g.ln_w[256 + t] + g.ln_b[256 + t];
        __syncthreads();
    }
}

extern "C" void kernel_launch(void* const* d_in, const int* in_sizes, int n_in,
                              void* d_out, int out_size, void* d_ws, size_t ws_size,
                              hipStream_t stream) {
    (void)in_sizes; (void)n_in; (void)out_size; (void)ws_size;
    float* ws = (float*)d_ws;

    Args a;
    a.x_m   = (const float*)d_in[0];
    a.x_c   = (const float*)d_in[1];
    a.b_m   = (const float*)d_in[2];
    a.b_c   = (const float*)d_in[3];
    a.bb_m  = (const float*)d_in[4];
    a.bb_c  = (const float*)d_in[5];
    a.p_m   = (const float*)d_in[6];
    a.p_c   = (const float*)d_in[7];
    a.W_xm  = (const float*)d_in[8];
    a.W_xc  = (const float*)d_in[9];
    a.W_bm  = (const float*)d_in[10];
    a.W_bc  = (const float*)d_in[11];
    a.Wq1_w = (const float*)d_in[12];
    a.Wq1_b = (const float*)d_in[13];
    a.Wq2_w = (const float*)d_in[14];
    a.Wq2_b = (const float*)d_in[15];
    a.Wk1_w = (const float*)d_in[16];
    a.Wk1_b = (const float*)d_in[17];
    a.Wk2_w = (const float*)d_in[18];
    a.Wk2_b = (const float*)d_in[19];
    a.mean_w = (const float*)d_in[20];
    a.mean_b = (const float*)d_in[21];
    a.cov_w  = (const float*)d_in[22];
    a.cov_b  = (const float*)d_in[23];
    a.ln_w   = (const float*)d_in[24];
    a.ln_b   = (const float*)d_in[25];
    a.b_seq  = (const int*)d_in[26];

    a.qkv = ws;
    a.pq  = ws + 786432;
    a.pk  = ws + 917504;
    a.bbq = ws + 1048576;
    a.bbk = ws + 1064960;
    a.fKm = ws + 1081344;
    a.fKs = ws + 1605632;
    a.y_m = ws + 2129920;
    a.y_c = ws + 2260992;
    a.A_m    = (unsigned short*)(ws + 2392064);
    a.A_c    = (unsigned short*)(ws + 2523136);
    a.Wt     = (unsigned short*)(ws + 2654208);
    a.wm_bf  = (unsigned short*)(ws + 4227072);
    a.wc_bf  = (unsigned short*)(ws + 4358144);
    a.mctxb  = (unsigned short*)(ws + 4489216);
    a.cctxb  = (unsigned short*)(ws + 4554752);
    a.pm_bf  = (unsigned short*)(ws + 4620288);
    a.bbm_bf = (unsigned short*)(ws + 4685824);
    a.w4_bf  = (unsigned short*)(ws + 4694016);
    a.out = (float*)d_out;

    // Cooperative launch guarantees co-residency for the software barrier.
    int maxb = 0;
    hipOccupancyMaxActiveBlocksPerMultiprocessor(&maxb, mega, 256, 0);
    int nblk = (maxb >= 2) ? 512 : 256;

    void* params[] = { (void*)&a };
    hipLaunchCooperativeKernel((void*)mega, dim3(nblk), dim3(256), params, 0u, stream);
}

// Round 11
// 206.429 us; speedup vs baseline: 3.4831x; 3.4831x over previous
//
#include <hip/hip_runtime.h>
#include <math.h>

#define B_ 2
#define S_ 128
#define H_ 4
#define DK_ 128
#define NB_ 4
#define D_ 512
#define M_ 256   // B_*S_

typedef __attribute__((ext_vector_type(8))) short short8;
typedef __attribute__((ext_vector_type(4))) float float4v;
typedef __attribute__((ext_vector_type(4))) unsigned short ushort4v;

__device__ __forceinline__ float elu1(float x) {
    return (x > 0.f) ? (x + 1.f) : __expf(x);
}

__device__ __forceinline__ unsigned short f2bf(float f) {
    unsigned u = __float_as_uint(f);
    unsigned r = (u + 0x7FFFu + ((u >> 16) & 1u)) >> 16;
    return (unsigned short)r;
}

// ---------------------------------------------------------------------------
// ws layout (float offsets)
//  qkv    : 786432   @ 0        | pq  131072 @ 786432 | pk 131072 @ 917504
//  bbq    : 16384    @ 1048576  | bbk 16384  @ 1064960
//  fKm    : 524288   @ 1081344  | fKs 524288 @ 1605632
//  (y_m/y_c slots retired — fin fused)
//  A_m    : 131072   @ 2392064  | A_c 131072 @ 2523136
//  Wt     : 1572864  @ 2654208  (bf16 [6][512][1024], n-major)
//  wm_bf  : 131072   @ 4227072  | wc_bf 131072 @ 4358144
//  mctxb  : 65536    @ 4489216  | cctxb 65536 @ 4554752
//  pm_bf  : 65536    @ 4620288  | bbm_bf 8192 @ 4685824
//  w4_bf  : 32768    @ 4694016  (bf16 [Wq2|Wk2|Wq1|Wk1], each 128x128 [n][k])
// ---------------------------------------------------------------------------

// ① prep: all bf16 conversions + projection-weight transpose. 768 blocks.
__global__ __launch_bounds__(256) void k_prep(
    const float* __restrict__ x_m, const float* __restrict__ b_m,
    const float* __restrict__ x_c, const float* __restrict__ b_c,
    const float* __restrict__ mean_w, const float* __restrict__ cov_w,
    const float* __restrict__ W_xm, const float* __restrict__ W_xc,
    const float* __restrict__ W_bm, const float* __restrict__ W_bc,
    const float* __restrict__ p_m, const float* __restrict__ bb_m,
    const float* __restrict__ Wq2, const float* __restrict__ Wk2,
    const float* __restrict__ Wq1, const float* __restrict__ Wk1,
    unsigned short* __restrict__ A_m, unsigned short* __restrict__ A_c,
    unsigned short* __restrict__ wm_bf, unsigned short* __restrict__ wc_bf,
    unsigned short* __restrict__ Wt,
    unsigned short* __restrict__ pm_bf, unsigned short* __restrict__ bbm_bf,
    unsigned short* __restrict__ w4_bf)
{
    __shared__ unsigned short tile[32][33];
    const int t = threadIdx.x;
    const int blk = blockIdx.x;
    const int NBK = gridDim.x;   // 768

    // A: bf16 conversions, 4 elems/chunk. 315392 chunks total.
    for (int cid = blk * 256 + t; cid < 315392; cid += NBK * 256) {
        const float* srcp;
        unsigned short* dstp;
        if (cid < 262144) {
            int job = cid >> 16;
            int off = (cid & 65535) * 4;
            if (job <= 1) {
                int m = off >> 10, k = off & 1023;
                if (job == 0) { srcp = (k < 512) ? (x_m + m * 512 + k) : (b_m + m * 512 + k - 512); dstp = A_m + off; }
                else          { srcp = (k < 512) ? (x_c + m * 512 + k) : (b_c + m * 512 + k - 512); dstp = A_c + off; }
            } else if (job == 2) { srcp = mean_w + off; dstp = wm_bf + off; }
            else                 { srcp = cov_w + off;  dstp = wc_bf + off; }
        } else if (cid < 294912) {
            int off = (cid - 262144) * 4;
            srcp = p_m + off; dstp = pm_bf + off;
        } else if (cid < 299008) {
            int off = (cid - 294912) * 4;
            srcp = bb_m + off; dstp = bbm_bf + off;
        } else {
            int off = (cid - 299008) * 4;
            int seg = off >> 14;             // 16384 elems each
            const float* Ws = (seg == 0) ? Wq2 : (seg == 1) ? Wk2 : (seg == 2) ? Wq1 : Wk1;
            srcp = Ws + (off & 16383); dstp = w4_bf + off;
        }
        float4 v = *(const float4*)srcp;
        ushort4v o4;
        o4.x = f2bf(v.x); o4.y = f2bf(v.y); o4.z = f2bf(v.z); o4.w = f2bf(v.w);
        *(ushort4v*)dstp = o4;
    }

    // B: projection-weight transpose+convert -> Wt[o][n][k]; 4 tiles/block.
    const int tx = t & 31, ty = t >> 5;
    for (int tid = blk; tid < 3072; tid += NBK) {
        int nt = tid & 15, kt = (tid >> 4) & 15, z = tid >> 8;
        int o = z >> 1, part = z & 1;
        const float* src;
        if (part == 0) src = (o < 3) ? (W_xm + o * 262144) : (W_xc + (o - 3) * 262144);
        else           src = (o < 3) ? (W_bm + o * 262144) : (W_bc + (o - 3) * 262144);
        __syncthreads();
#pragma unroll
        for (int u = 0; u < 4; ++u)
            tile[ty + u * 8][tx] = f2bf(src[(kt * 32 + ty + u * 8) * 512 + nt * 32 + tx]);
        __syncthreads();
        unsigned short* dst = Wt + o * 524288 + part * 512;
#pragma unroll
        for (int u = 0; u < 4; ++u)
            dst[(nt * 32 + ty + u * 8) * 1024 + kt * 32 + tx] = tile[tx][ty + u * 8];
    }
}

// ② MFMA GEMM: jobs 0..3071 = qkv projections (K=1024);
//    3072..4095 = pq/pk lins (K=128); 4096..4223 = bbq/bbk lins.
__global__ __launch_bounds__(256) void k_mm(
    const unsigned short* __restrict__ A_m, const unsigned short* __restrict__ A_c,
    const unsigned short* __restrict__ Wt,
    const unsigned short* __restrict__ pm_bf, const unsigned short* __restrict__ bbm_bf,
    const unsigned short* __restrict__ w4_bf,
    const float* __restrict__ bq2, const float* __restrict__ bk2,
    const float* __restrict__ bq1, const float* __restrict__ bk1,
    float* __restrict__ qkv, float* __restrict__ pq, float* __restrict__ pk,
    float* __restrict__ bbq, float* __restrict__ bbk)
{
    const int t = threadIdx.x;
    const int wid = blockIdx.x * 4 + (t >> 6);
    const int lane = t & 63;
    const int l15 = lane & 15, quad = lane >> 4;

    if (wid < 3072) {
        const int o = wid >> 9;
        const int rem = wid & 511;
        const int nt = rem & 31, mt = rem >> 5;
        const int m0 = mt * 16, n0 = nt * 16;

        const unsigned short* A = (o < 3) ? A_m : A_c;
        const unsigned short* ap = A + (m0 + l15) * 1024 + quad * 8;
        const unsigned short* bp = Wt + o * 524288 + (n0 + l15) * 1024 + quad * 8;

        float4v acc0 = {0.f, 0.f, 0.f, 0.f};
        float4v acc1 = {0.f, 0.f, 0.f, 0.f};
#pragma unroll
        for (int k0 = 0; k0 < 1024; k0 += 64) {
            short8 a0 = *(const short8*)(ap + k0);
            short8 b0 = *(const short8*)(bp + k0);
            short8 a1 = *(const short8*)(ap + k0 + 32);
            short8 b1 = *(const short8*)(bp + k0 + 32);
            acc0 = __builtin_amdgcn_mfma_f32_16x16x32_bf16(a0, b0, acc0, 0, 0, 0);
            acc1 = __builtin_amdgcn_mfma_f32_16x16x32_bf16(a1, b1, acc1, 0, 0, 0);
        }
        float* dst = qkv + o * 131072;
#pragma unroll
        for (int r = 0; r < 4; ++r) {
            float v = acc0[r] + acc1[r];
            if (o >= 3) v = elu1(v);
            dst[(m0 + quad * 4 + r) * 512 + n0 + l15] = v;
        }
    } else {
        const unsigned short* Abf;
        const unsigned short* Wb;
        const float* bias;
        float* dst;
        int m0, n0, h;
        if (wid < 4096) {
            int lid = wid - 3072;
            int sel = lid >> 9;              // 0=pq(Wq2), 1=pk(Wk2)
            int r = lid & 511;
            h = r >> 7;
            int rem = r & 127;
            m0 = (rem >> 3) * 16; n0 = (rem & 7) * 16;
            Abf = pm_bf;
            Wb = w4_bf + sel * 16384;
            bias = sel ? bk2 : bq2;
            dst = sel ? pk : pq;
        } else {
            int lid = wid - 4096;
            int sel = lid >> 6;              // 0=bbq(Wq1), 1=bbk(Wk1)
            int r = lid & 63;
            h = r >> 4;
            int rem = r & 15;
            m0 = (rem >> 3) * 16; n0 = (rem & 7) * 16;
            Abf = bbm_bf;
            Wb = w4_bf + 32768 + sel * 16384;
            bias = sel ? bk1 : bq1;
            dst = sel ? bbk : bbq;
        }
        const unsigned short* ap = Abf + (m0 + l15) * 512 + h * 128 + quad * 8;
        const unsigned short* bp = Wb + (n0 + l15) * 128 + quad * 8;

        float4v acc0 = {0.f, 0.f, 0.f, 0.f};
        float4v acc1 = {0.f, 0.f, 0.f, 0.f};
#pragma unroll
        for (int k0 = 0; k0 < 128; k0 += 64) {
            short8 a0 = *(const short8*)(ap + k0);
            short8 b0 = *(const short8*)(bp + k0);
            short8 a1 = *(const short8*)(ap + k0 + 32);
            short8 b1 = *(const short8*)(bp + k0 + 32);
            acc0 = __builtin_amdgcn_mfma_f32_16x16x32_bf16(a0, b0, acc0, 0, 0, 0);
            acc1 = __builtin_amdgcn_mfma_f32_16x16x32_bf16(a1, b1, acc1, 0, 0, 0);
        }
        float bv = bias[n0 + l15];
#pragma unroll
        for (int r = 0; r < 4; ++r)
            dst[(m0 + quad * 4 + r) * 512 + h * 128 + n0 + l15] = acc0[r] + acc1[r] + bv;
    }
}

// ③ fK precompute (tri-SAGP, K-side): S*NB work. Block (j,h,b), thread=dim.
__global__ __launch_bounds__(128) void k_fuseK(
    const float* __restrict__ qkv, const float* __restrict__ pk,
    const float* __restrict__ bbk, const float* __restrict__ bb_c,
    const float* __restrict__ p_c, const int* __restrict__ b_seq,
    float* __restrict__ fKm, float* __restrict__ fKs)
{
    const int t = threadIdx.x;
    const int j = blockIdx.x, h = blockIdx.y, b = blockIdx.z;
    const int d = h * 128 + t;
    const float eps = 1e-24f;
    const int base = (b * S_ + j) * D_ + d;
    const int sj = b_seq[b * S_ + j];

    float m1 = qkv[M_ * D_ + base];        // k1
    float c1 = qkv[4 * M_ * D_ + base];    // k2 (elu'd)
    float m3 = pk[base];
    float c3 = p_c[base];

    float p1 = 1.f / fmaxf(c1, eps);
    float p3 = 1.f / fmaxf(c3, eps);
    float mp13 = m1 * p1 + m3 * p3;

#pragma unroll
    for (int sv = 0; sv < 4; ++sv) {
        int idx = (b * 16 + sj * 4 + sv) * 512 + d;   // n1=seq[j], n2=sv(=si)
        float m2 = bbk[idx];
        float c2 = bb_c[idx];
        float p2 = 1.f / fmaxf(c2, eps);
        float cc = 1.f / (p1 + p2 + p3);
        int o = (((b * H_ + h) * 4 + sv) * S_ + j) * 128 + t;   // [B,H,NB,S,DK]
        fKm[o] = cc * (mp13 + m2 * p2);
        fKs[o] = sqrtf(fmaxf(cc, eps));
    }
}

// ④ attn: fQ inline + fK from ws; softmax; ctx. Block (i,h,b).
__global__ __launch_bounds__(128) void k_attn3(
    const float* __restrict__ qkv, const float* __restrict__ pq,
    const float* __restrict__ bbq, const float* __restrict__ bb_c,
    const float* __restrict__ p_c, const int* __restrict__ b_seq,
    const float* __restrict__ fKm, const float* __restrict__ fKs,
    float* __restrict__ probs_out, unsigned short* __restrict__ mctxb,
    unsigned short* __restrict__ cctxb)
{
    const int t = threadIdx.x;
    const int i = blockIdx.x, h = blockIdx.y, b = blockIdx.z;
    const float eps = 1e-24f;

    __shared__ __attribute__((aligned(16))) float qm[4 * 132];
    __shared__ __attribute__((aligned(16))) float qs[4 * 132];
    __shared__ float red[4];
    __shared__ float pr[128], pr2[128];

    const int si = b_seq[b * S_ + i];
    const int sj = b_seq[b * S_ + t];

    // fQ(i, sv) -> LDS (thread t = dim)
    {
        const int d = h * 128 + t;
        const int base = (b * S_ + i) * D_ + d;
        float m1 = qkv[base];                  // q1
        float c1 = qkv[3 * M_ * D_ + base];    // q2 (elu'd)
        float m3 = pq[base];
        float c3 = p_c[base];
        float p1 = 1.f / fmaxf(c1, eps);
        float p3 = 1.f / fmaxf(c3, eps);
        float mp13 = m1 * p1 + m3 * p3;
#pragma unroll
        for (int sv = 0; sv < 4; ++sv) {
            int idx = (b * 16 + sv * 4 + si) * 512 + d;   // n1=sv, n2=seq[i]
            float m2 = bbq[idx];
            float c2 = bb_c[idx];
            float p2 = 1.f / fmaxf(c2, eps);
            float cc = 1.f / (p1 + p2 + p3);
            qm[sv * 132 + t] = cc * (mp13 + m2 * p2);
            qs[sv * 132 + t] = sqrtf(fmaxf(cc, eps));
        }
    }
    __syncthreads();

    const int krow = (((b * H_ + h) * 4 + si) * S_ + t) * 128;
    const float4* kmp = (const float4*)(fKm + krow);
    const float4* ksp = (const float4*)(fKs + krow);

    float w2 = 0.f;
#pragma unroll 4
    for (int k4 = 0; k4 < 32; ++k4) {
        float4 km = kmp[k4];
        float4 ks = ksp[k4];
        float4 m = *(const float4*)&qm[sj * 132 + k4 * 4];
        float4 s = *(const float4*)&qs[sj * 132 + k4 * 4];
        float d0 = m.x - km.x, d1 = m.y - km.y, d2 = m.z - km.z, d3 = m.w - km.w;
        float e0 = s.x - ks.x, e1 = s.y - ks.y, e2 = s.z - ks.z, e3 = s.w - ks.w;
        w2 += d0 * d0 + d1 * d1 + d2 * d2 + d3 * d3
            + e0 * e0 + e1 * e1 + e2 * e2 + e3 * e3;
    }
    float score = -w2 * 0.08838834764831845f;   // 1/sqrt(128)

    float mx = score;
#pragma unroll
    for (int off = 32; off >= 1; off >>= 1) mx = fmaxf(mx, __shfl_xor(mx, off));
    if ((t & 63) == 0) red[t >> 6] = mx;
    __syncthreads();
    mx = fmaxf(red[0], red[1]);
    float e = __expf(score - mx);
    float sm = e;
#pragma unroll
    for (int off = 32; off >= 1; off >>= 1) sm += __shfl_xor(sm, off);
    if ((t & 63) == 0) red[2 + (t >> 6)] = sm;
    __syncthreads();
    float p = e / (red[2] + red[3]);

    probs_out[((b * H_ + h) * S_ + i) * S_ + t] = p;
    pr[t] = p;
    pr2[t] = p * p;
    __syncthreads();

    const float* v1 = qkv + 2 * M_ * D_ + (b * S_) * D_ + h * 128 + t;
    const float* v2 = qkv + 5 * M_ * D_ + (b * S_) * D_ + h * 128 + t;
    float am = 0.f, ac = 0.f;
#pragma unroll 8
    for (int j = 0; j < 128; ++j) {
        am = fmaf(pr[j], v1[j * D_], am);
        ac = fmaf(pr2[j], v2[j * D_], ac);
    }
    mctxb[(b * S_ + i) * D_ + h * 128 + t] = f2bf(am);
    cctxb[(b * S_ + i) * D_ + h * 128 + t] = f2bf(ac);
}

// ⑤ fused epilogue: MFMA GEMM (y into LDS) + bias + residual + LN -> out.
//    Block = (mat, 16-row mtile); 32 blocks x 256 threads. (R5-proven body.)
__global__ __launch_bounds__(256) void k_fin(
    const unsigned short* __restrict__ mctxb, const unsigned short* __restrict__ cctxb,
    const unsigned short* __restrict__ wm_bf, const unsigned short* __restrict__ wc_bf,
    const float* __restrict__ mean_b, const float* __restrict__ cov_b,
    const float* __restrict__ x_m, const float* __restrict__ x_c,
    const float* __restrict__ ln_w, const float* __restrict__ ln_b,
    float* __restrict__ out)
{
    const int mat = blockIdx.x >> 4, mt = blockIdx.x & 15;
    const int m0 = mt * 16;
    const unsigned short* A = mat ? cctxb : mctxb;
    const unsigned short* Bw = mat ? wc_bf : wm_bf;

    __shared__ float y[16][516];   // +4 pad spreads banks across rows

    const int t = threadIdx.x;
    const int wv = t >> 6, lane = t & 63;
    const int l15 = lane & 15, quad = lane >> 4;

    const unsigned short* ap = A + (m0 + l15) * 512 + quad * 8;
#pragma unroll
    for (int u = 0; u < 8; ++u) {
        int n0 = (wv * 8 + u) * 16;
        const unsigned short* bp = Bw + (n0 + l15) * 512 + quad * 8;
        float4v acc0 = {0.f, 0.f, 0.f, 0.f};
        float4v acc1 = {0.f, 0.f, 0.f, 0.f};
#pragma unroll
        for (int k0 = 0; k0 < 512; k0 += 64) {
            short8 a0 = *(const short8*)(ap + k0);
            short8 b0 = *(const short8*)(bp + k0);
            short8 a1 = *(const short8*)(ap + k0 + 32);
            short8 b1 = *(const short8*)(bp + k0 + 32);
            acc0 = __builtin_amdgcn_mfma_f32_16x16x32_bf16(a0, b0, acc0, 0, 0, 0);
            acc1 = __builtin_amdgcn_mfma_f32_16x16x32_bf16(a1, b1, acc1, 0, 0, 0);
        }
#pragma unroll
        for (int r = 0; r < 4; ++r)
            y[quad * 4 + r][n0 + l15] = acc0[r] + acc1[r];
    }
    __syncthreads();

    // LN: thread (r = t>>4, c = t&15): 32 cols each, 16-lane shuffle reduce.
    const int r = t >> 4, c = t & 15;
    const int row = m0 + r;
    const float* bias = mat ? cov_b : mean_b;
    const float* res = mat ? x_c : x_m;

    float vals[32];
    float s = 0.f, ss = 0.f;
#pragma unroll
    for (int u = 0; u < 32; ++u) {
        int col = c + 16 * u;
        float v = y[r][col] + bias[col] + res[row * 512 + col];
        vals[u] = v;
        s += v; ss += v * v;
    }
#pragma unroll
    for (int off = 8; off >= 1; off >>= 1) {
        s += __shfl_xor(s, off);
        ss += __shfl_xor(ss, off);
    }
    float mu = s * (1.f / 512.f);
    float var = ss * (1.f / 512.f) - mu * mu;
    float rstd = 1.f / sqrtf(var + 1e-12f);
#pragma unroll
    for (int u = 0; u < 32; ++u) {
        int col = c + 16 * u;
        out[mat * 131072 + row * 512 + col] = (vals[u] - mu) * rstd * ln_w[col] + ln_b[col];
    }
}

extern "C" void kernel_launch(void* const* d_in, const int* in_sizes, int n_in,
                              void* d_out, int out_size, void* d_ws, size_t ws_size,
                              hipStream_t stream) {
    (void)in_sizes; (void)n_in; (void)out_size; (void)ws_size;
    const float* x_m   = (const float*)d_in[0];
    const float* x_c   = (const float*)d_in[1];
    const float* b_m   = (const float*)d_in[2];
    const float* b_c   = (const float*)d_in[3];
    const float* bb_m  = (const float*)d_in[4];
    const float* bb_c  = (const float*)d_in[5];
    const float* p_m   = (const float*)d_in[6];
    const float* p_c   = (const float*)d_in[7];
    const float* W_xm  = (const float*)d_in[8];
    const float* W_xc  = (const float*)d_in[9];
    const float* W_bm  = (const float*)d_in[10];
    const float* W_bc  = (const float*)d_in[11];
    const float* Wq1_w = (const float*)d_in[12];
    const float* Wq1_b = (const float*)d_in[13];
    const float* Wq2_w = (const float*)d_in[14];
    const float* Wq2_b = (const float*)d_in[15];
    const float* Wk1_w = (const float*)d_in[16];
    const float* Wk1_b = (const float*)d_in[17];
    const float* Wk2_w = (const float*)d_in[18];
    const float* Wk2_b = (const float*)d_in[19];
    const float* mean_w = (const float*)d_in[20];
    const float* mean_b = (const float*)d_in[21];
    const float* cov_w  = (const float*)d_in[22];
    const float* cov_b  = (const float*)d_in[23];
    const float* ln_w   = (const float*)d_in[24];
    const float* ln_b   = (const float*)d_in[25];
    const int*   b_seq  = (const int*)d_in[26];

    float* ws = (float*)d_ws;
    float* qkv = ws;
    float* pq  = ws + 786432;
    float* pk  = ws + 917504;
    float* bbq = ws + 1048576;
    float* bbk = ws + 1064960;
    float* fKm = ws + 1081344;
    float* fKs = ws + 1605632;
    unsigned short* A_m    = (unsigned short*)(ws + 2392064);
    unsigned short* A_c    = (unsigned short*)(ws + 2523136);
    unsigned short* Wt     = (unsigned short*)(ws + 2654208);
    unsigned short* wm_bf  = (unsigned short*)(ws + 4227072);
    unsigned short* wc_bf  = (unsigned short*)(ws + 4358144);
    unsigned short* mctxb  = (unsigned short*)(ws + 4489216);
    unsigned short* cctxb  = (unsigned short*)(ws + 4554752);
    unsigned short* pm_bf  = (unsigned short*)(ws + 4620288);
    unsigned short* bbm_bf = (unsigned short*)(ws + 4685824);
    unsigned short* w4_bf  = (unsigned short*)(ws + 4694016);
    float* out = (float*)d_out;

    k_prep<<<dim3(768), 256, 0, stream>>>(
        x_m, b_m, x_c, b_c, mean_w, cov_w, W_xm, W_xc, W_bm, W_bc,
        p_m, bb_m, Wq2_w, Wk2_w, Wq1_w, Wk1_w,
        A_m, A_c, wm_bf, wc_bf, Wt, pm_bf, bbm_bf, w4_bf);
    k_mm<<<dim3(1056), 256, 0, stream>>>(
        A_m, A_c, Wt, pm_bf, bbm_bf, w4_bf,
        Wq2_b, Wk2_b, Wq1_b, Wk1_b,
        qkv, pq, pk, bbq, bbk);
    k_fuseK<<<dim3(128, 4, 2), 128, 0, stream>>>(
        qkv, pk, bbk, bb_c, p_c, b_seq, fKm, fKs);
    k_attn3<<<dim3(128, 4, 2), 128, 0, stream>>>(
        qkv, pq, bbq, bb_c, p_c, b_seq, fKm, fKs, out + 262144, mctxb, cctxb);
    k_fin<<<dim3(32), 256, 0, stream>>>(
        mctxb, cctxb, wm_bf, wc_bf, mean_b, cov_b, x_m, x_c, ln_w, ln_b, out);
}

// Round 12
// 195.264 us; speedup vs baseline: 3.6823x; 1.0572x over previous
//
#include <hip/hip_runtime.h>
#include <math.h>

#define B_ 2
#define S_ 128
#define H_ 4
#define DK_ 128
#define NB_ 4
#define D_ 512
#define M_ 256   // B_*S_

typedef __attribute__((ext_vector_type(8))) short short8;
typedef __attribute__((ext_vector_type(4))) float float4v;
typedef __attribute__((ext_vector_type(4))) unsigned short ushort4v;

__device__ __forceinline__ float elu1(float x) {
    return (x > 0.f) ? (x + 1.f) : __expf(x);
}

__device__ __forceinline__ unsigned short f2bf(float f) {
    unsigned u = __float_as_uint(f);
    unsigned r = (u + 0x7FFFu + ((u >> 16) & 1u)) >> 16;
    return (unsigned short)r;
}

// ---------------------------------------------------------------------------
// ws layout (float offsets) — identical to R9
//  qkv 786432@0 | pq 131072@786432 | pk 131072@917504 | bbq 16384@1048576
//  bbk 16384@1064960 | fKm 524288@1081344 | fKs 524288@1605632
//  A_m 131072@2392064 | A_c 131072@2523136 | Wt 1572864@2654208
//  wm_bf 131072@4227072 | wc_bf 131072@4358144 | mctxb 65536@4489216
//  cctxb 65536@4554752 | pm_bf 65536@4620288 | bbm_bf 8192@4685824
//  w4_bf 32768@4694016
// ---------------------------------------------------------------------------

// ① prep: all bf16 conversions + projection-weight transpose. 768 blocks.
__global__ __launch_bounds__(256) void k_prep(
    const float* __restrict__ x_m, const float* __restrict__ b_m,
    const float* __restrict__ x_c, const float* __restrict__ b_c,
    const float* __restrict__ mean_w, const float* __restrict__ cov_w,
    const float* __restrict__ W_xm, const float* __restrict__ W_xc,
    const float* __restrict__ W_bm, const float* __restrict__ W_bc,
    const float* __restrict__ p_m, const float* __restrict__ bb_m,
    const float* __restrict__ Wq2, const float* __restrict__ Wk2,
    const float* __restrict__ Wq1, const float* __restrict__ Wk1,
    unsigned short* __restrict__ A_m, unsigned short* __restrict__ A_c,
    unsigned short* __restrict__ wm_bf, unsigned short* __restrict__ wc_bf,
    unsigned short* __restrict__ Wt,
    unsigned short* __restrict__ pm_bf, unsigned short* __restrict__ bbm_bf,
    unsigned short* __restrict__ w4_bf)
{
    __shared__ unsigned short tile[32][33];
    const int t = threadIdx.x;
    const int blk = blockIdx.x;
    const int NBK = gridDim.x;   // 768

    // A: bf16 conversions, 4 elems/chunk. 315392 chunks total.
    for (int cid = blk * 256 + t; cid < 315392; cid += NBK * 256) {
        const float* srcp;
        unsigned short* dstp;
        if (cid < 262144) {
            int job = cid >> 16;
            int off = (cid & 65535) * 4;
            if (job <= 1) {
                int m = off >> 10, k = off & 1023;
                if (job == 0) { srcp = (k < 512) ? (x_m + m * 512 + k) : (b_m + m * 512 + k - 512); dstp = A_m + off; }
                else          { srcp = (k < 512) ? (x_c + m * 512 + k) : (b_c + m * 512 + k - 512); dstp = A_c + off; }
            } else if (job == 2) { srcp = mean_w + off; dstp = wm_bf + off; }
            else                 { srcp = cov_w + off;  dstp = wc_bf + off; }
        } else if (cid < 294912) {
            int off = (cid - 262144) * 4;
            srcp = p_m + off; dstp = pm_bf + off;
        } else if (cid < 299008) {
            int off = (cid - 294912) * 4;
            srcp = bb_m + off; dstp = bbm_bf + off;
        } else {
            int off = (cid - 299008) * 4;
            int seg = off >> 14;             // 16384 elems each
            const float* Ws = (seg == 0) ? Wq2 : (seg == 1) ? Wk2 : (seg == 2) ? Wq1 : Wk1;
            srcp = Ws + (off & 16383); dstp = w4_bf + off;
        }
        float4 v = *(const float4*)srcp;
        ushort4v o4;
        o4.x = f2bf(v.x); o4.y = f2bf(v.y); o4.z = f2bf(v.z); o4.w = f2bf(v.w);
        *(ushort4v*)dstp = o4;
    }

    // B: projection-weight transpose+convert -> Wt[o][n][k]; 4 tiles/block.
    const int tx = t & 31, ty = t >> 5;
    for (int tid = blk; tid < 3072; tid += NBK) {
        int nt = tid & 15, kt = (tid >> 4) & 15, z = tid >> 8;
        int o = z >> 1, part = z & 1;
        const float* src;
        if (part == 0) src = (o < 3) ? (W_xm + o * 262144) : (W_xc + (o - 3) * 262144);
        else           src = (o < 3) ? (W_bm + o * 262144) : (W_bc + (o - 3) * 262144);
        __syncthreads();
#pragma unroll
        for (int u = 0; u < 4; ++u)
            tile[ty + u * 8][tx] = f2bf(src[(kt * 32 + ty + u * 8) * 512 + nt * 32 + tx]);
        __syncthreads();
        unsigned short* dst = Wt + o * 524288 + part * 512;
#pragma unroll
        for (int u = 0; u < 4; ++u)
            dst[(nt * 32 + ty + u * 8) * 1024 + kt * 32 + tx] = tile[tx][ty + u * 8];
    }
}

// ② MFMA GEMM: jobs 0..3071 = qkv projections (K=1024);
//    3072..4095 = pq/pk lins (K=128); 4096..4223 = bbq/bbk lins.
__global__ __launch_bounds__(256) void k_mm(
    const unsigned short* __restrict__ A_m, const unsigned short* __restrict__ A_c,
    const unsigned short* __restrict__ Wt,
    const unsigned short* __restrict__ pm_bf, const unsigned short* __restrict__ bbm_bf,
    const unsigned short* __restrict__ w4_bf,
    const float* __restrict__ bq2, const float* __restrict__ bk2,
    const float* __restrict__ bq1, const float* __restrict__ bk1,
    float* __restrict__ qkv, float* __restrict__ pq, float* __restrict__ pk,
    float* __restrict__ bbq, float* __restrict__ bbk)
{
    const int t = threadIdx.x;
    const int wid = blockIdx.x * 4 + (t >> 6);
    const int lane = t & 63;
    const int l15 = lane & 15, quad = lane >> 4;

    if (wid < 3072) {
        const int o = wid >> 9;
        const int rem = wid & 511;
        const int nt = rem & 31, mt = rem >> 5;
        const int m0 = mt * 16, n0 = nt * 16;

        const unsigned short* A = (o < 3) ? A_m : A_c;
        const unsigned short* ap = A + (m0 + l15) * 1024 + quad * 8;
        const unsigned short* bp = Wt + o * 524288 + (n0 + l15) * 1024 + quad * 8;

        float4v acc0 = {0.f, 0.f, 0.f, 0.f};
        float4v acc1 = {0.f, 0.f, 0.f, 0.f};
#pragma unroll
        for (int k0 = 0; k0 < 1024; k0 += 64) {
            short8 a0 = *(const short8*)(ap + k0);
            short8 b0 = *(const short8*)(bp + k0);
            short8 a1 = *(const short8*)(ap + k0 + 32);
            short8 b1 = *(const short8*)(bp + k0 + 32);
            acc0 = __builtin_amdgcn_mfma_f32_16x16x32_bf16(a0, b0, acc0, 0, 0, 0);
            acc1 = __builtin_amdgcn_mfma_f32_16x16x32_bf16(a1, b1, acc1, 0, 0, 0);
        }
        float* dst = qkv + o * 131072;
#pragma unroll
        for (int r = 0; r < 4; ++r) {
            float v = acc0[r] + acc1[r];
            if (o >= 3) v = elu1(v);
            dst[(m0 + quad * 4 + r) * 512 + n0 + l15] = v;
        }
    } else {
        const unsigned short* Abf;
        const unsigned short* Wb;
        const float* bias;
        float* dst;
        int m0, n0, h;
        if (wid < 4096) {
            int lid = wid - 3072;
            int sel = lid >> 9;              // 0=pq(Wq2), 1=pk(Wk2)
            int r = lid & 511;
            h = r >> 7;
            int rem = r & 127;
            m0 = (rem >> 3) * 16; n0 = (rem & 7) * 16;
            Abf = pm_bf;
            Wb = w4_bf + sel * 16384;
            bias = sel ? bk2 : bq2;
            dst = sel ? pk : pq;
        } else {
            int lid = wid - 4096;
            int sel = lid >> 6;              // 0=bbq(Wq1), 1=bbk(Wk1)
            int r = lid & 63;
            h = r >> 4;
            int rem = r & 15;
            m0 = (rem >> 3) * 16; n0 = (rem & 7) * 16;
            Abf = bbm_bf;
            Wb = w4_bf + 32768 + sel * 16384;
            bias = sel ? bk1 : bq1;
            dst = sel ? bbk : bbq;
        }
        const unsigned short* ap = Abf + (m0 + l15) * 512 + h * 128 + quad * 8;
        const unsigned short* bp = Wb + (n0 + l15) * 128 + quad * 8;

        float4v acc0 = {0.f, 0.f, 0.f, 0.f};
        float4v acc1 = {0.f, 0.f, 0.f, 0.f};
#pragma unroll
        for (int k0 = 0; k0 < 128; k0 += 64) {
            short8 a0 = *(const short8*)(ap + k0);
            short8 b0 = *(const short8*)(bp + k0);
            short8 a1 = *(const short8*)(ap + k0 + 32);
            short8 b1 = *(const short8*)(bp + k0 + 32);
            acc0 = __builtin_amdgcn_mfma_f32_16x16x32_bf16(a0, b0, acc0, 0, 0, 0);
            acc1 = __builtin_amdgcn_mfma_f32_16x16x32_bf16(a1, b1, acc1, 0, 0, 0);
        }
        float bv = bias[n0 + l15];
#pragma unroll
        for (int r = 0; r < 4; ++r)
            dst[(m0 + quad * 4 + r) * 512 + h * 128 + n0 + l15] = acc0[r] + acc1[r] + bv;
    }
}

// ③ fK precompute (tri-SAGP, K-side): S*NB work. Block (j,h,b), thread=dim.
__global__ __launch_bounds__(128) void k_fuseK(
    const float* __restrict__ qkv, const float* __restrict__ pk,
    const float* __restrict__ bbk, const float* __restrict__ bb_c,
    const float* __restrict__ p_c, const int* __restrict__ b_seq,
    float* __restrict__ fKm, float* __restrict__ fKs)
{
    const int t = threadIdx.x;
    const int j = blockIdx.x, h = blockIdx.y, b = blockIdx.z;
    const int d = h * 128 + t;
    const float eps = 1e-24f;
    const int base = (b * S_ + j) * D_ + d;
    const int sj = b_seq[b * S_ + j];

    float m1 = qkv[M_ * D_ + base];        // k1
    float c1 = qkv[4 * M_ * D_ + base];    // k2 (elu'd)
    float m3 = pk[base];
    float c3 = p_c[base];

    float p1 = 1.f / fmaxf(c1, eps);
    float p3 = 1.f / fmaxf(c3, eps);
    float mp13 = m1 * p1 + m3 * p3;

#pragma unroll
    for (int sv = 0; sv < 4; ++sv) {
        int idx = (b * 16 + sj * 4 + sv) * 512 + d;   // n1=seq[j], n2=sv(=si)
        float m2 = bbk[idx];
        float c2 = bb_c[idx];
        float p2 = 1.f / fmaxf(c2, eps);
        float cc = 1.f / (p1 + p2 + p3);
        int o = (((b * H_ + h) * 4 + sv) * S_ + j) * 128 + t;   // [B,H,NB,S,DK]
        fKm[o] = cc * (mp13 + m2 * p2);
        fKs[o] = sqrtf(fmaxf(cc, eps));
    }
}

// ④ attn: fQ inline + fK from ws; softmax; ctx. Block (i,h,b).
__global__ __launch_bounds__(128) void k_attn3(
    const float* __restrict__ qkv, const float* __restrict__ pq,
    const float* __restrict__ bbq, const float* __restrict__ bb_c,
    const float* __restrict__ p_c, const int* __restrict__ b_seq,
    const float* __restrict__ fKm, const float* __restrict__ fKs,
    float* __restrict__ probs_out, unsigned short* __restrict__ mctxb,
    unsigned short* __restrict__ cctxb)
{
    const int t = threadIdx.x;
    const int i = blockIdx.x, h = blockIdx.y, b = blockIdx.z;
    const float eps = 1e-24f;

    __shared__ __attribute__((aligned(16))) float qm[4 * 132];
    __shared__ __attribute__((aligned(16))) float qs[4 * 132];
    __shared__ float red[4];
    __shared__ float pr[128], pr2[128];

    const int si = b_seq[b * S_ + i];
    const int sj = b_seq[b * S_ + t];

    // fQ(i, sv) -> LDS (thread t = dim)
    {
        const int d = h * 128 + t;
        const int base = (b * S_ + i) * D_ + d;
        float m1 = qkv[base];                  // q1
        float c1 = qkv[3 * M_ * D_ + base];    // q2 (elu'd)
        float m3 = pq[base];
        float c3 = p_c[base];
        float p1 = 1.f / fmaxf(c1, eps);
        float p3 = 1.f / fmaxf(c3, eps);
        float mp13 = m1 * p1 + m3 * p3;
#pragma unroll
        for (int sv = 0; sv < 4; ++sv) {
            int idx = (b * 16 + sv * 4 + si) * 512 + d;   // n1=sv, n2=seq[i]
            float m2 = bbq[idx];
            float c2 = bb_c[idx];
            float p2 = 1.f / fmaxf(c2, eps);
            float cc = 1.f / (p1 + p2 + p3);
            qm[sv * 132 + t] = cc * (mp13 + m2 * p2);
            qs[sv * 132 + t] = sqrtf(fmaxf(cc, eps));
        }
    }
    __syncthreads();

    const int krow = (((b * H_ + h) * 4 + si) * S_ + t) * 128;
    const float4* kmp = (const float4*)(fKm + krow);
    const float4* ksp = (const float4*)(fKs + krow);

    float w2 = 0.f;
#pragma unroll 4
    for (int k4 = 0; k4 < 32; ++k4) {
        float4 km = kmp[k4];
        float4 ks = ksp[k4];
        float4 m = *(const float4*)&qm[sj * 132 + k4 * 4];
        float4 s = *(const float4*)&qs[sj * 132 + k4 * 4];
        float d0 = m.x - km.x, d1 = m.y - km.y, d2 = m.z - km.z, d3 = m.w - km.w;
        float e0 = s.x - ks.x, e1 = s.y - ks.y, e2 = s.z - ks.z, e3 = s.w - ks.w;
        w2 += d0 * d0 + d1 * d1 + d2 * d2 + d3 * d3
            + e0 * e0 + e1 * e1 + e2 * e2 + e3 * e3;
    }
    float score = -w2 * 0.08838834764831845f;   // 1/sqrt(128)

    float mx = score;
#pragma unroll
    for (int off = 32; off >= 1; off >>= 1) mx = fmaxf(mx, __shfl_xor(mx, off));
    if ((t & 63) == 0) red[t >> 6] = mx;
    __syncthreads();
    mx = fmaxf(red[0], red[1]);
    float e = __expf(score - mx);
    float sm = e;
#pragma unroll
    for (int off = 32; off >= 1; off >>= 1) sm += __shfl_xor(sm, off);
    if ((t & 63) == 0) red[2 + (t >> 6)] = sm;
    __syncthreads();
    float p = e / (red[2] + red[3]);

    probs_out[((b * H_ + h) * S_ + i) * S_ + t] = p;
    pr[t] = p;
    pr2[t] = p * p;
    __syncthreads();

    const float* v1 = qkv + 2 * M_ * D_ + (b * S_) * D_ + h * 128 + t;
    const float* v2 = qkv + 5 * M_ * D_ + (b * S_) * D_ + h * 128 + t;
    float am = 0.f, ac = 0.f;
#pragma unroll 8
    for (int j = 0; j < 128; ++j) {
        am = fmaf(pr[j], v1[j * D_], am);
        ac = fmaf(pr2[j], v2[j * D_], ac);
    }
    mctxb[(b * S_ + i) * D_ + h * 128 + t] = f2bf(am);
    cctxb[(b * S_ + i) * D_ + h * 128 + t] = f2bf(ac);
}

// ⑤ fused epilogue v2: MFMA GEMM + bias + residual + LN, 512 threads (8 waves)
//    per block — 2x the wave parallelism of R11's failed 256-thread variant.
//    Block = (mat, 16-row mtile); 32 blocks.
__global__ __launch_bounds__(512) void k_fin(
    const unsigned short* __restrict__ mctxb, const unsigned short* __restrict__ cctxb,
    const unsigned short* __restrict__ wm_bf, const unsigned short* __restrict__ wc_bf,
    const float* __restrict__ mean_b, const float* __restrict__ cov_b,
    const float* __restrict__ x_m, const float* __restrict__ x_c,
    const float* __restrict__ ln_w, const float* __restrict__ ln_b,
    float* __restrict__ out)
{
    const int mat = blockIdx.x >> 4, mt = blockIdx.x & 15;
    const int m0 = mt * 16;
    const unsigned short* A = mat ? cctxb : mctxb;
    const unsigned short* Bw = mat ? wc_bf : wm_bf;

    __shared__ float y[16][516];   // +4 pad spreads banks across rows

    const int t = threadIdx.x;
    const int wv = t >> 6, lane = t & 63;     // 8 waves
    const int l15 = lane & 15, quad = lane >> 4;

    const unsigned short* ap = A + (m0 + l15) * 512 + quad * 8;
#pragma unroll
    for (int u = 0; u < 4; ++u) {
        int n0 = (wv * 4 + u) * 16;           // 8 waves x 4 jobs = 32 n-tiles
        const unsigned short* bp = Bw + (n0 + l15) * 512 + quad * 8;
        float4v acc0 = {0.f, 0.f, 0.f, 0.f};
        float4v acc1 = {0.f, 0.f, 0.f, 0.f};
#pragma unroll
        for (int k0 = 0; k0 < 512; k0 += 64) {
            short8 a0 = *(const short8*)(ap + k0);
            short8 b0 = *(const short8*)(bp + k0);
            short8 a1 = *(const short8*)(ap + k0 + 32);
            short8 b1 = *(const short8*)(bp + k0 + 32);
            acc0 = __builtin_amdgcn_mfma_f32_16x16x32_bf16(a0, b0, acc0, 0, 0, 0);
            acc1 = __builtin_amdgcn_mfma_f32_16x16x32_bf16(a1, b1, acc1, 0, 0, 0);
        }
#pragma unroll
        for (int r = 0; r < 4; ++r)
            y[quad * 4 + r][n0 + l15] = acc0[r] + acc1[r];
    }
    __syncthreads();

    // LN: 512 threads = 16 rows x 32 lanes; each lane 16 cols; 32-lane reduce
    // (32-lane groups align with row boundaries inside each wave).
    const int r = t >> 5, c = t & 31;
    const int row = m0 + r;
    const float* bias = mat ? cov_b : mean_b;
    const float* res = mat ? x_c : x_m;

    float vals[16];
    float s = 0.f, ss = 0.f;
#pragma unroll
    for (int u = 0; u < 16; ++u) {
        int col = c + 32 * u;
        float v = y[r][col] + bias[col] + res[row * 512 + col];
        vals[u] = v;
        s += v; ss += v * v;
    }
#pragma unroll
    for (int off = 16; off >= 1; off >>= 1) {
        s += __shfl_xor(s, off);
        ss += __shfl_xor(ss, off);
    }
    float mu = s * (1.f / 512.f);
    float var = ss * (1.f / 512.f) - mu * mu;
    float rstd = 1.f / sqrtf(var + 1e-12f);
#pragma unroll
    for (int u = 0; u < 16; ++u) {
        int col = c + 32 * u;
        out[mat * 131072 + row * 512 + col] = (vals[u] - mu) * rstd * ln_w[col] + ln_b[col];
    }
}

extern "C" void kernel_launch(void* const* d_in, const int* in_sizes, int n_in,
                              void* d_out, int out_size, void* d_ws, size_t ws_size,
                              hipStream_t stream) {
    (void)in_sizes; (void)n_in; (void)out_size; (void)ws_size;
    const float* x_m   = (const float*)d_in[0];
    const float* x_c   = (const float*)d_in[1];
    const float* b_m   = (const float*)d_in[2];
    const float* b_c   = (const float*)d_in[3];
    const float* bb_m  = (const float*)d_in[4];
    const float* bb_c  = (const float*)d_in[5];
    const float* p_m   = (const float*)d_in[6];
    const float* p_c   = (const float*)d_in[7];
    const float* W_xm  = (const float*)d_in[8];
    const float* W_xc  = (const float*)d_in[9];
    const float* W_bm  = (const float*)d_in[10];
    const float* W_bc  = (const float*)d_in[11];
    const float* Wq1_w = (const float*)d_in[12];
    const float* Wq1_b = (const float*)d_in[13];
    const float* Wq2_w = (const float*)d_in[14];
    const float* Wq2_b = (const float*)d_in[15];
    const float* Wk1_w = (const float*)d_in[16];
    const float* Wk1_b = (const float*)d_in[17];
    const float* Wk2_w = (const float*)d_in[18];
    const float* Wk2_b = (const float*)d_in[19];
    const float* mean_w = (const float*)d_in[20];
    const float* mean_b = (const float*)d_in[21];
    const float* cov_w  = (const float*)d_in[22];
    const float* cov_b  = (const float*)d_in[23];
    const float* ln_w   = (const float*)d_in[24];
    const float* ln_b   = (const float*)d_in[25];
    const int*   b_seq  = (const int*)d_in[26];

    float* ws = (float*)d_ws;
    float* qkv = ws;
    float* pq  = ws + 786432;
    float* pk  = ws + 917504;
    float* bbq = ws + 1048576;
    float* bbk = ws + 1064960;
    float* fKm = ws + 1081344;
    float* fKs = ws + 1605632;
    unsigned short* A_m    = (unsigned short*)(ws + 2392064);
    unsigned short* A_c    = (unsigned short*)(ws + 2523136);
    unsigned short* Wt     = (unsigned short*)(ws + 2654208);
    unsigned short* wm_bf  = (unsigned short*)(ws + 4227072);
    unsigned short* wc_bf  = (unsigned short*)(ws + 4358144);
    unsigned short* mctxb  = (unsigned short*)(ws + 4489216);
    unsigned short* cctxb  = (unsigned short*)(ws + 4554752);
    unsigned short* pm_bf  = (unsigned short*)(ws + 4620288);
    unsigned short* bbm_bf = (unsigned short*)(ws + 4685824);
    unsigned short* w4_bf  = (unsigned short*)(ws + 4694016);
    float* out = (float*)d_out;

    k_prep<<<dim3(768), 256, 0, stream>>>(
        x_m, b_m, x_c, b_c, mean_w, cov_w, W_xm, W_xc, W_bm, W_bc,
        p_m, bb_m, Wq2_w, Wk2_w, Wq1_w, Wk1_w,
        A_m, A_c, wm_bf, wc_bf, Wt, pm_bf, bbm_bf, w4_bf);
    k_mm<<<dim3(1056), 256, 0, stream>>>(
        A_m, A_c, Wt, pm_bf, bbm_bf, w4_bf,
        Wq2_b, Wk2_b, Wq1_b, Wk1_b,
        qkv, pq, pk, bbq, bbk);
    k_fuseK<<<dim3(128, 4, 2), 128, 0, stream>>>(
        qkv, pk, bbk, bb_c, p_c, b_seq, fKm, fKs);
    k_attn3<<<dim3(128, 4, 2), 128, 0, stream>>>(
        qkv, pq, bbq, bb_c, p_c, b_seq, fKm, fKs, out + 262144, mctxb, cctxb);
    k_fin<<<dim3(32), 512, 0, stream>>>(
        mctxb, cctxb, wm_bf, wc_bf, mean_b, cov_b, x_m, x_c, ln_w, ln_b, out);
}

// Round 13
// 177.086 us; speedup vs baseline: 4.0603x; 1.1027x over previous
//
#include <hip/hip_runtime.h>
#include <math.h>

#define B_ 2
#define S_ 128
#define H_ 4
#define DK_ 128
#define NB_ 4
#define D_ 512
#define M_ 256   // B_*S_

typedef __attribute__((ext_vector_type(8))) short short8;
typedef __attribute__((ext_vector_type(4))) float float4v;
typedef __attribute__((ext_vector_type(4))) unsigned short ushort4v;

__device__ __forceinline__ float elu1(float x) {
    return (x > 0.f) ? (x + 1.f) : __expf(x);
}

__device__ __forceinline__ unsigned short f2bf(float f) {
    unsigned u = __float_as_uint(f);
    unsigned r = (u + 0x7FFFu + ((u >> 16) & 1u)) >> 16;
    return (unsigned short)r;
}

// ---------------------------------------------------------------------------
// ws layout (float offsets) — identical to R9
//  qkv 786432@0 | pq 131072@786432 | pk 131072@917504 | bbq 16384@1048576
//  bbk 16384@1064960 | fKm 524288@1081344 | fKs 524288@1605632
//  y_m 131072@2129920 | y_c 131072@2260992 | A_m 131072@2392064
//  A_c 131072@2523136 | Wt 1572864@2654208 | wm_bf 131072@4227072
//  wc_bf 131072@4358144 | mctxb 65536@4489216 | cctxb 65536@4554752
//  pm_bf 65536@4620288 | bbm_bf 8192@4685824 | w4_bf 32768@4694016
// ---------------------------------------------------------------------------

// ① prep: all bf16 conversions + projection-weight transpose. 768 blocks.
//    Part B batches its 4 tile-transposes: one latency chain + one sync
//    instead of four (R13 micro-opt; math identical).
__global__ __launch_bounds__(256) void k_prep(
    const float* __restrict__ x_m, const float* __restrict__ b_m,
    const float* __restrict__ x_c, const float* __restrict__ b_c,
    const float* __restrict__ mean_w, const float* __restrict__ cov_w,
    const float* __restrict__ W_xm, const float* __restrict__ W_xc,
    const float* __restrict__ W_bm, const float* __restrict__ W_bc,
    const float* __restrict__ p_m, const float* __restrict__ bb_m,
    const float* __restrict__ Wq2, const float* __restrict__ Wk2,
    const float* __restrict__ Wq1, const float* __restrict__ Wk1,
    unsigned short* __restrict__ A_m, unsigned short* __restrict__ A_c,
    unsigned short* __restrict__ wm_bf, unsigned short* __restrict__ wc_bf,
    unsigned short* __restrict__ Wt,
    unsigned short* __restrict__ pm_bf, unsigned short* __restrict__ bbm_bf,
    unsigned short* __restrict__ w4_bf)
{
    __shared__ unsigned short tile4[4][32][33];
    const int t = threadIdx.x;
    const int blk = blockIdx.x;
    const int NBK = gridDim.x;   // must be 768 (3072 tiles = 4*768)

    // A: bf16 conversions, 4 elems/chunk. 315392 chunks total.
    for (int cid = blk * 256 + t; cid < 315392; cid += NBK * 256) {
        const float* srcp;
        unsigned short* dstp;
        if (cid < 262144) {
            int job = cid >> 16;
            int off = (cid & 65535) * 4;
            if (job <= 1) {
                int m = off >> 10, k = off & 1023;
                if (job == 0) { srcp = (k < 512) ? (x_m + m * 512 + k) : (b_m + m * 512 + k - 512); dstp = A_m + off; }
                else          { srcp = (k < 512) ? (x_c + m * 512 + k) : (b_c + m * 512 + k - 512); dstp = A_c + off; }
            } else if (job == 2) { srcp = mean_w + off; dstp = wm_bf + off; }
            else                 { srcp = cov_w + off;  dstp = wc_bf + off; }
        } else if (cid < 294912) {
            int off = (cid - 262144) * 4;
            srcp = p_m + off; dstp = pm_bf + off;
        } else if (cid < 299008) {
            int off = (cid - 294912) * 4;
            srcp = bb_m + off; dstp = bbm_bf + off;
        } else {
            int off = (cid - 299008) * 4;
            int seg = off >> 14;             // 16384 elems each
            const float* Ws = (seg == 0) ? Wq2 : (seg == 1) ? Wk2 : (seg == 2) ? Wq1 : Wk1;
            srcp = Ws + (off & 16383); dstp = w4_bf + off;
        }
        float4 v = *(const float4*)srcp;
        ushort4v o4;
        o4.x = f2bf(v.x); o4.y = f2bf(v.y); o4.z = f2bf(v.z); o4.w = f2bf(v.w);
        *(ushort4v*)dstp = o4;
    }

    // B: projection-weight transpose+convert -> Wt[o][n][k]; 4 tiles/block,
    // batched loads -> single sync -> batched stores.
    const int tx = t & 31, ty = t >> 5;
#pragma unroll
    for (int it = 0; it < 4; ++it) {
        int tid = blk + it * 768;
        int nt = tid & 15, kt = (tid >> 4) & 15, z = tid >> 8;
        int o = z >> 1, part = z & 1;
        const float* src;
        if (part == 0) src = (o < 3) ? (W_xm + o * 262144) : (W_xc + (o - 3) * 262144);
        else           src = (o < 3) ? (W_bm + o * 262144) : (W_bc + (o - 3) * 262144);
#pragma unroll
        for (int u = 0; u < 4; ++u)
            tile4[it][ty + u * 8][tx] = f2bf(src[(kt * 32 + ty + u * 8) * 512 + nt * 32 + tx]);
    }
    __syncthreads();
#pragma unroll
    for (int it = 0; it < 4; ++it) {
        int tid = blk + it * 768;
        int nt = tid & 15, kt = (tid >> 4) & 15, z = tid >> 8;
        int o = z >> 1, part = z & 1;
        unsigned short* dst = Wt + o * 524288 + part * 512;
#pragma unroll
        for (int u = 0; u < 4; ++u)
            dst[(nt * 32 + ty + u * 8) * 1024 + kt * 32 + tx] = tile4[it][tx][ty + u * 8];
    }
}

// ② MFMA GEMM: jobs 0..3071 = qkv projections (K=1024);
//    3072..4095 = pq/pk lins (K=128); 4096..4223 = bbq/bbk lins.
__global__ __launch_bounds__(256) void k_mm(
    const unsigned short* __restrict__ A_m, const unsigned short* __restrict__ A_c,
    const unsigned short* __restrict__ Wt,
    const unsigned short* __restrict__ pm_bf, const unsigned short* __restrict__ bbm_bf,
    const unsigned short* __restrict__ w4_bf,
    const float* __restrict__ bq2, const float* __restrict__ bk2,
    const float* __restrict__ bq1, const float* __restrict__ bk1,
    float* __restrict__ qkv, float* __restrict__ pq, float* __restrict__ pk,
    float* __restrict__ bbq, float* __restrict__ bbk)
{
    const int t = threadIdx.x;
    const int wid = blockIdx.x * 4 + (t >> 6);
    const int lane = t & 63;
    const int l15 = lane & 15, quad = lane >> 4;

    if (wid < 3072) {
        const int o = wid >> 9;
        const int rem = wid & 511;
        const int nt = rem & 31, mt = rem >> 5;
        const int m0 = mt * 16, n0 = nt * 16;

        const unsigned short* A = (o < 3) ? A_m : A_c;
        const unsigned short* ap = A + (m0 + l15) * 1024 + quad * 8;
        const unsigned short* bp = Wt + o * 524288 + (n0 + l15) * 1024 + quad * 8;

        float4v acc0 = {0.f, 0.f, 0.f, 0.f};
        float4v acc1 = {0.f, 0.f, 0.f, 0.f};
#pragma unroll
        for (int k0 = 0; k0 < 1024; k0 += 64) {
            short8 a0 = *(const short8*)(ap + k0);
            short8 b0 = *(const short8*)(bp + k0);
            short8 a1 = *(const short8*)(ap + k0 + 32);
            short8 b1 = *(const short8*)(bp + k0 + 32);
            acc0 = __builtin_amdgcn_mfma_f32_16x16x32_bf16(a0, b0, acc0, 0, 0, 0);
            acc1 = __builtin_amdgcn_mfma_f32_16x16x32_bf16(a1, b1, acc1, 0, 0, 0);
        }
        float* dst = qkv + o * 131072;
#pragma unroll
        for (int r = 0; r < 4; ++r) {
            float v = acc0[r] + acc1[r];
            if (o >= 3) v = elu1(v);
            dst[(m0 + quad * 4 + r) * 512 + n0 + l15] = v;
        }
    } else {
        const unsigned short* Abf;
        const unsigned short* Wb;
        const float* bias;
        float* dst;
        int m0, n0, h;
        if (wid < 4096) {
            int lid = wid - 3072;
            int sel = lid >> 9;              // 0=pq(Wq2), 1=pk(Wk2)
            int r = lid & 511;
            h = r >> 7;
            int rem = r & 127;
            m0 = (rem >> 3) * 16; n0 = (rem & 7) * 16;
            Abf = pm_bf;
            Wb = w4_bf + sel * 16384;
            bias = sel ? bk2 : bq2;
            dst = sel ? pk : pq;
        } else {
            int lid = wid - 4096;
            int sel = lid >> 6;              // 0=bbq(Wq1), 1=bbk(Wk1)
            int r = lid & 63;
            h = r >> 4;
            int rem = r & 15;
            m0 = (rem >> 3) * 16; n0 = (rem & 7) * 16;
            Abf = bbm_bf;
            Wb = w4_bf + 32768 + sel * 16384;
            bias = sel ? bk1 : bq1;
            dst = sel ? bbk : bbq;
        }
        const unsigned short* ap = Abf + (m0 + l15) * 512 + h * 128 + quad * 8;
        const unsigned short* bp = Wb + (n0 + l15) * 128 + quad * 8;

        float4v acc0 = {0.f, 0.f, 0.f, 0.f};
        float4v acc1 = {0.f, 0.f, 0.f, 0.f};
#pragma unroll
        for (int k0 = 0; k0 < 128; k0 += 64) {
            short8 a0 = *(const short8*)(ap + k0);
            short8 b0 = *(const short8*)(bp + k0);
            short8 a1 = *(const short8*)(ap + k0 + 32);
            short8 b1 = *(const short8*)(bp + k0 + 32);
            acc0 = __builtin_amdgcn_mfma_f32_16x16x32_bf16(a0, b0, acc0, 0, 0, 0);
            acc1 = __builtin_amdgcn_mfma_f32_16x16x32_bf16(a1, b1, acc1, 0, 0, 0);
        }
        float bv = bias[n0 + l15];
#pragma unroll
        for (int r = 0; r < 4; ++r)
            dst[(m0 + quad * 4 + r) * 512 + h * 128 + n0 + l15] = acc0[r] + acc1[r] + bv;
    }
}

// ③ fK precompute (tri-SAGP, K-side): S*NB work. Block (j,h,b), thread=dim.
__global__ __launch_bounds__(128) void k_fuseK(
    const float* __restrict__ qkv, const float* __restrict__ pk,
    const float* __restrict__ bbk, const float* __restrict__ bb_c,
    const float* __restrict__ p_c, const int* __restrict__ b_seq,
    float* __restrict__ fKm, float* __restrict__ fKs)
{
    const int t = threadIdx.x;
    const int j = blockIdx.x, h = blockIdx.y, b = blockIdx.z;
    const int d = h * 128 + t;
    const float eps = 1e-24f;
    const int base = (b * S_ + j) * D_ + d;
    const int sj = b_seq[b * S_ + j];

    float m1 = qkv[M_ * D_ + base];        // k1
    float c1 = qkv[4 * M_ * D_ + base];    // k2 (elu'd)
    float m3 = pk[base];
    float c3 = p_c[base];

    float p1 = 1.f / fmaxf(c1, eps);
    float p3 = 1.f / fmaxf(c3, eps);
    float mp13 = m1 * p1 + m3 * p3;

#pragma unroll
    for (int sv = 0; sv < 4; ++sv) {
        int idx = (b * 16 + sj * 4 + sv) * 512 + d;   // n1=seq[j], n2=sv(=si)
        float m2 = bbk[idx];
        float c2 = bb_c[idx];
        float p2 = 1.f / fmaxf(c2, eps);
        float cc = 1.f / (p1 + p2 + p3);
        int o = (((b * H_ + h) * 4 + sv) * S_ + j) * 128 + t;   // [B,H,NB,S,DK]
        fKm[o] = cc * (mp13 + m2 * p2);
        fKs[o] = sqrtf(fmaxf(cc, eps));
    }
}

// ④ attn: fQ inline + fK from ws; softmax; ctx. Block (i,h,b).
__global__ __launch_bounds__(128) void k_attn3(
    const float* __restrict__ qkv, const float* __restrict__ pq,
    const float* __restrict__ bbq, const float* __restrict__ bb_c,
    const float* __restrict__ p_c, const int* __restrict__ b_seq,
    const float* __restrict__ fKm, const float* __restrict__ fKs,
    float* __restrict__ probs_out, unsigned short* __restrict__ mctxb,
    unsigned short* __restrict__ cctxb)
{
    const int t = threadIdx.x;
    const int i = blockIdx.x, h = blockIdx.y, b = blockIdx.z;
    const float eps = 1e-24f;

    __shared__ __attribute__((aligned(16))) float qm[4 * 132];
    __shared__ __attribute__((aligned(16))) float qs[4 * 132];
    __shared__ float red[4];
    __shared__ float pr[128], pr2[128];

    const int si = b_seq[b * S_ + i];
    const int sj = b_seq[b * S_ + t];

    // fQ(i, sv) -> LDS (thread t = dim)
    {
        const int d = h * 128 + t;
        const int base = (b * S_ + i) * D_ + d;
        float m1 = qkv[base];                  // q1
        float c1 = qkv[3 * M_ * D_ + base];    // q2 (elu'd)
        float m3 = pq[base];
        float c3 = p_c[base];
        float p1 = 1.f / fmaxf(c1, eps);
        float p3 = 1.f / fmaxf(c3, eps);
        float mp13 = m1 * p1 + m3 * p3;
#pragma unroll
        for (int sv = 0; sv < 4; ++sv) {
            int idx = (b * 16 + sv * 4 + si) * 512 + d;   // n1=sv, n2=seq[i]
            float m2 = bbq[idx];
            float c2 = bb_c[idx];
            float p2 = 1.f / fmaxf(c2, eps);
            float cc = 1.f / (p1 + p2 + p3);
            qm[sv * 132 + t] = cc * (mp13 + m2 * p2);
            qs[sv * 132 + t] = sqrtf(fmaxf(cc, eps));
        }
    }
    __syncthreads();

    const int krow = (((b * H_ + h) * 4 + si) * S_ + t) * 128;
    const float4* kmp = (const float4*)(fKm + krow);
    const float4* ksp = (const float4*)(fKs + krow);

    float w2 = 0.f;
#pragma unroll 4
    for (int k4 = 0; k4 < 32; ++k4) {
        float4 km = kmp[k4];
        float4 ks = ksp[k4];
        float4 m = *(const float4*)&qm[sj * 132 + k4 * 4];
        float4 s = *(const float4*)&qs[sj * 132 + k4 * 4];
        float d0 = m.x - km.x, d1 = m.y - km.y, d2 = m.z - km.z, d3 = m.w - km.w;
        float e0 = s.x - ks.x, e1 = s.y - ks.y, e2 = s.z - ks.z, e3 = s.w - ks.w;
        w2 += d0 * d0 + d1 * d1 + d2 * d2 + d3 * d3
            + e0 * e0 + e1 * e1 + e2 * e2 + e3 * e3;
    }
    float score = -w2 * 0.08838834764831845f;   // 1/sqrt(128)

    float mx = score;
#pragma unroll
    for (int off = 32; off >= 1; off >>= 1) mx = fmaxf(mx, __shfl_xor(mx, off));
    if ((t & 63) == 0) red[t >> 6] = mx;
    __syncthreads();
    mx = fmaxf(red[0], red[1]);
    float e = __expf(score - mx);
    float sm = e;
#pragma unroll
    for (int off = 32; off >= 1; off >>= 1) sm += __shfl_xor(sm, off);
    if ((t & 63) == 0) red[2 + (t >> 6)] = sm;
    __syncthreads();
    float p = e / (red[2] + red[3]);

    probs_out[((b * H_ + h) * S_ + i) * S_ + t] = p;
    pr[t] = p;
    pr2[t] = p * p;
    __syncthreads();

    const float* v1 = qkv + 2 * M_ * D_ + (b * S_) * D_ + h * 128 + t;
    const float* v2 = qkv + 5 * M_ * D_ + (b * S_) * D_ + h * 128 + t;
    float am = 0.f, ac = 0.f;
#pragma unroll 8
    for (int j = 0; j < 128; ++j) {
        am = fmaf(pr[j], v1[j * D_], am);
        ac = fmaf(pr2[j], v2[j * D_], ac);
    }
    mctxb[(b * S_ + i) * D_ + h * 128 + t] = f2bf(am);
    cctxb[(b * S_ + i) * D_ + h * 128 + t] = f2bf(ac);
}

// ⑤ epilogue MFMA GEMM: full K per wave, direct store. 1024 waves.
__global__ __launch_bounds__(256) void k_fin_mm(
    const unsigned short* __restrict__ mctxb, const unsigned short* __restrict__ cctxb,
    const unsigned short* __restrict__ wm_bf, const unsigned short* __restrict__ wc_bf,
    float* __restrict__ y_m, float* __restrict__ y_c)
{
    const int t = threadIdx.x;
    const int wid = blockIdx.x * 4 + (t >> 6);
    const int lane = t & 63;
    const int mat = wid >> 9;
    const int rem = wid & 511;
    const int nt = rem & 31, mt = rem >> 5;
    const int m0 = mt * 16, n0 = nt * 16;
    const int l15 = lane & 15, quad = lane >> 4;

    const unsigned short* A = mat ? cctxb : mctxb;
    const unsigned short* Bw = mat ? wc_bf : wm_bf;
    float* y = mat ? y_c : y_m;

    const unsigned short* ap = A + (m0 + l15) * 512 + quad * 8;
    const unsigned short* bp = Bw + (n0 + l15) * 512 + quad * 8;

    float4v acc0 = {0.f, 0.f, 0.f, 0.f};
    float4v acc1 = {0.f, 0.f, 0.f, 0.f};
#pragma unroll
    for (int k0 = 0; k0 < 512; k0 += 64) {
        short8 a0 = *(const short8*)(ap + k0);
        short8 b0 = *(const short8*)(bp + k0);
        short8 a1 = *(const short8*)(ap + k0 + 32);
        short8 b1 = *(const short8*)(bp + k0 + 32);
        acc0 = __builtin_amdgcn_mfma_f32_16x16x32_bf16(a0, b0, acc0, 0, 0, 0);
        acc1 = __builtin_amdgcn_mfma_f32_16x16x32_bf16(a1, b1, acc1, 0, 0, 0);
    }
#pragma unroll
    for (int r = 0; r < 4; ++r)
        y[(m0 + quad * 4 + r) * 512 + n0 + l15] = acc0[r] + acc1[r];
}

// ⑥ bias + residual + LayerNorm -> out. One block per output row (512 rows).
__global__ __launch_bounds__(256) void k_ln(
    const float* __restrict__ y_m, const float* __restrict__ y_c,
    const float* __restrict__ mean_b, const float* __restrict__ cov_b,
    const float* __restrict__ x_m, const float* __restrict__ x_c,
    const float* __restrict__ ln_w, const float* __restrict__ ln_b,
    float* __restrict__ out)
{
    const int t = threadIdx.x;
    const int id = blockIdx.x;
    const int mat = id >> 8, row = id & 255;
    const float* yg = mat ? y_c : y_m;
    const float* bias = mat ? cov_b : mean_b;
    const float* res = mat ? x_c : x_m;
    const int base = row * 512;

    __shared__ float red[8];

    float y0 = yg[base + t] + bias[t] + res[base + t];
    float y1 = yg[base + 256 + t] + bias[256 + t] + res[base + 256 + t];
    float s = y0 + y1, ss = y0 * y0 + y1 * y1;
#pragma unroll
    for (int off = 32; off >= 1; off >>= 1) { s += __shfl_xor(s, off); ss += __shfl_xor(ss, off); }
    if ((t & 63) == 0) { red[t >> 6] = s; red[4 + (t >> 6)] = ss; }
    __syncthreads();
    float mu = (red[0] + red[1] + red[2] + red[3]) * (1.f / 512.f);
    float var = (red[4] + red[5] + red[6] + red[7]) * (1.f / 512.f) - mu * mu;
    float rstd = 1.f / sqrtf(var + 1e-12f);
    out[mat * 131072 + base + t] = (y0 - mu) * rstd * ln_w[t] + ln_b[t];
    out[mat * 131072 + base + 256 + t] = (y1 - mu) * rstd * ln_w[256 + t] + ln_b[256 + t];
}

extern "C" void kernel_launch(void* const* d_in, const int* in_sizes, int n_in,
                              void* d_out, int out_size, void* d_ws, size_t ws_size,
                              hipStream_t stream) {
    (void)in_sizes; (void)n_in; (void)out_size; (void)ws_size;
    const float* x_m   = (const float*)d_in[0];
    const float* x_c   = (const float*)d_in[1];
    const float* b_m   = (const float*)d_in[2];
    const float* b_c   = (const float*)d_in[3];
    const float* bb_m  = (const float*)d_in[4];
    const float* bb_c  = (const float*)d_in[5];
    const float* p_m   = (const float*)d_in[6];
    const float* p_c   = (const float*)d_in[7];
    const float* W_xm  = (const float*)d_in[8];
    const float* W_xc  = (const float*)d_in[9];
    const float* W_bm  = (const float*)d_in[10];
    const float* W_bc  = (const float*)d_in[11];
    const float* Wq1_w = (const float*)d_in[12];
    const float* Wq1_b = (const float*)d_in[13];
    const float* Wq2_w = (const float*)d_in[14];
    const float* Wq2_b = (const float*)d_in[15];
    const float* Wk1_w = (const float*)d_in[16];
    const float* Wk1_b = (const float*)d_in[17];
    const float* Wk2_w = (const float*)d_in[18];
    const float* Wk2_b = (const float*)d_in[19];
    const float* mean_w = (const float*)d_in[20];
    const float* mean_b = (const float*)d_in[21];
    const float* cov_w  = (const float*)d_in[22];
    const float* cov_b  = (const float*)d_in[23];
    const float* ln_w   = (const float*)d_in[24];
    const float* ln_b   = (const float*)d_in[25];
    const int*   b_seq  = (const int*)d_in[26];

    float* ws = (float*)d_ws;
    float* qkv = ws;
    float* pq  = ws + 786432;
    float* pk  = ws + 917504;
    float* bbq = ws + 1048576;
    float* bbk = ws + 1064960;
    float* fKm = ws + 1081344;
    float* fKs = ws + 1605632;
    float* y_m = ws + 2129920;
    float* y_c = ws + 2260992;
    unsigned short* A_m    = (unsigned short*)(ws + 2392064);
    unsigned short* A_c    = (unsigned short*)(ws + 2523136);
    unsigned short* Wt     = (unsigned short*)(ws + 2654208);
    unsigned short* wm_bf  = (unsigned short*)(ws + 4227072);
    unsigned short* wc_bf  = (unsigned short*)(ws + 4358144);
    unsigned short* mctxb  = (unsigned short*)(ws + 4489216);
    unsigned short* cctxb  = (unsigned short*)(ws + 4554752);
    unsigned short* pm_bf  = (unsigned short*)(ws + 4620288);
    unsigned short* bbm_bf = (unsigned short*)(ws + 4685824);
    unsigned short* w4_bf  = (unsigned short*)(ws + 4694016);
    float* out = (float*)d_out;

    k_prep<<<dim3(768), 256, 0, stream>>>(
        x_m, b_m, x_c, b_c, mean_w, cov_w, W_xm, W_xc, W_bm, W_bc,
        p_m, bb_m, Wq2_w, Wk2_w, Wq1_w, Wk1_w,
        A_m, A_c, wm_bf, wc_bf, Wt, pm_bf, bbm_bf, w4_bf);
    k_mm<<<dim3(1056), 256, 0, stream>>>(
        A_m, A_c, Wt, pm_bf, bbm_bf, w4_bf,
        Wq2_b, Wk2_b, Wq1_b, Wk1_b,
        qkv, pq, pk, bbq, bbk);
    k_fuseK<<<dim3(128, 4, 2), 128, 0, stream>>>(
        qkv, pk, bbk, bb_c, p_c, b_seq, fKm, fKs);
    k_attn3<<<dim3(128, 4, 2), 128, 0, stream>>>(
        qkv, pq, bbq, bb_c, p_c, b_seq, fKm, fKs, out + 262144, mctxb, cctxb);
    k_fin_mm<<<dim3(256), 256, 0, stream>>>(
        mctxb, cctxb, wm_bf, wc_bf, y_m, y_c);
    k_ln<<<dim3(512), 256, 0, stream>>>(
        y_m, y_c, mean_b, cov_b, x_m, x_c, ln_w, ln_b, out);
}